// Round 8
// baseline (217.164 us; speedup 1.0000x reference)
//
#include <hip/hip_runtime.h>

typedef float floatx4 __attribute__((ext_vector_type(4)));
typedef long longx2 __attribute__((ext_vector_type(2)));

#define GN 4096
#define GK 1024
#define BM 128
#define BN 128
#define INVT (1.0f/0.03f)
#define NTILES 528      // 32*33/2 upper-tri tiles per modality
#define NCROSS 1024     // 32*32 cross tiles

// OCP e4m3 byte -> f32 (inputs are satfinite converts of N(0,1); no NaN)
static __device__ __forceinline__ float fp8dec(unsigned b) {
    unsigned s = (b >> 7) & 1u, e = (b >> 3) & 0xFu, m = b & 7u;
    float v;
    if (e == 0) v = (float)m * 0.001953125f;                       // m * 2^-9
    else v = __builtin_bit_cast(float, ((e + 120u) << 23) | (m << 20));
    return s ? -v : v;
}

// One block per index i: quantize post-row i AND brand-row i, compute both
// inv-norms and the cross-diag dot in a single pass.
__global__ __launch_bounds__(256)
void prep_all(const float* __restrict__ brand, const float* __restrict__ post,
              unsigned char* __restrict__ brandq, unsigned char* __restrict__ postq,
              float* __restrict__ inv_brand, float* __restrict__ inv_post,
              float* __restrict__ dvec) {
    const int i = blockIdx.x, tid = threadIdx.x;
    const int wave = tid >> 6, lane = tid & 63;
    __shared__ float swp[4], swb[4], swd[4];

    float4 pv = ((const float4*)(post  + (size_t)i * GK))[tid];
    float4 bv = ((const float4*)(brand + (size_t)i * GK))[tid];
    int p = __builtin_amdgcn_cvt_pk_fp8_f32(pv.x, pv.y, 0, false);
    p = __builtin_amdgcn_cvt_pk_fp8_f32(pv.z, pv.w, p, true);
    int q = __builtin_amdgcn_cvt_pk_fp8_f32(bv.x, bv.y, 0, false);
    q = __builtin_amdgcn_cvt_pk_fp8_f32(bv.z, bv.w, q, true);
    ((int*)(postq  + (size_t)i * GK))[tid] = p;
    ((int*)(brandq + (size_t)i * GK))[tid] = q;

    float p0 = fp8dec(p & 0xFF), p1 = fp8dec((p >> 8) & 0xFF);
    float p2 = fp8dec((p >> 16) & 0xFF), p3 = fp8dec((p >> 24) & 0xFF);
    float b0 = fp8dec(q & 0xFF), b1 = fp8dec((q >> 8) & 0xFF);
    float b2 = fp8dec((q >> 16) & 0xFF), b3 = fp8dec((q >> 24) & 0xFF);
    float ssp = p0 * p0 + p1 * p1 + p2 * p2 + p3 * p3;
    float ssb = b0 * b0 + b1 * b1 + b2 * b2 + b3 * b3;
    float ssd = p0 * b0 + p1 * b1 + p2 * b2 + p3 * b3;
    #pragma unroll
    for (int off = 32; off > 0; off >>= 1) {
        ssp += __shfl_down(ssp, off);
        ssb += __shfl_down(ssb, off);
        ssd += __shfl_down(ssd, off);
    }
    if (lane == 0) { swp[wave] = ssp; swb[wave] = ssb; swd[wave] = ssd; }
    __syncthreads();
    if (tid == 0) {
        inv_post[i]  = 1.0f / sqrtf(swp[0] + swp[1] + swp[2] + swp[3]);
        inv_brand[i] = 1.0f / sqrtf(swb[0] + swb[1] + swb[2] + swb[3]);
        dvec[i]      = swd[0] + swd[1] + swd[2] + swd[3];
    }
}

// Unified GEMM dispatch, fp8 e4m3 16x16x32, NO LDS tile / NO K-loop barriers.
// Fragments load straight from global (L2/L3-resident 8 MB inputs).
// k-permutation trick: per 64-B k-window, MFMA sub0 consumes the low 8 B of
// each 16-B chunk, sub1 the high 8 B (same perm for A and B -> same dot
// product), so lane (lrow,kq) reads one contiguous dwordx4 [16kq,16kq+16)
// and each load instruction covers 16 full 64-B lines.
__global__ __launch_bounds__(256)
void gemm_all(const unsigned char* __restrict__ postq, const unsigned char* __restrict__ brandq,
              const float* __restrict__ dvec,
              const float* __restrict__ inv_post, const float* __restrict__ inv_brand,
              float* __restrict__ sum_post, float* __restrict__ cnt_post,
              float* __restrict__ sum_brand, float* __restrict__ cnt_brand,
              float* __restrict__ cnt_dummy) {
    __shared__ float s_ia[128], s_ib[128], s_da[128], s_db[128];
    __shared__ float redRS[128][2], redRC[128][2], redCS[128][2], redCC[128][2];

    const int tid = threadIdx.x;
    const int wave = tid >> 6, lane = tid & 63;
    const int wm = (wave >> 1) * 64, wn = (wave & 1) * 64;

    int idx = blockIdx.x;
    const unsigned char *A, *B;
    float *srow, *scol, *crow, *ccol;
    int bm, bn;
    bool fix_diag, do_cols;

    if (idx < NCROSS) {
        fix_diag = false; do_cols = true;
        bm = (idx >> 5) * BM; bn = (idx & 31) * BN;
        A = postq; B = brandq;
        srow = sum_post; crow = cnt_post; scol = sum_brand; ccol = cnt_brand;
        if (tid < 128) { s_ia[tid] = inv_post[bm + tid] * INVT; s_da[tid] = dvec[bm + tid]; }
        else { int t2 = tid - 128; s_ib[t2] = inv_brand[bn + t2]; s_db[t2] = dvec[bn + t2]; }
    } else {
        fix_diag = true;
        idx -= NCROSS;
        const unsigned char* X; const float* invx; float* sacc;
        if (idx >= NTILES) { idx -= NTILES; X = brandq; invx = inv_brand; sacc = sum_brand; }
        else               {               X = postq;  invx = inv_post;  sacc = sum_post;  }
        int J = (int)((sqrtf(8.f * idx + 1.f) - 1.f) * 0.5f);
        while ((J + 1) * (J + 2) / 2 <= idx) ++J;
        while (J * (J + 1) / 2 > idx) --J;
        const int I = idx - J * (J + 1) / 2;
        bm = I * BM; bn = J * BN;
        A = X; B = X;
        srow = sacc; scol = sacc; crow = cnt_dummy; ccol = cnt_dummy;
        do_cols = (I != J);
        // sentinel diag: counts compare s > 1e30 -> always 0
        if (tid < 128) { s_ia[tid] = invx[bm + tid] * (0.8f * INVT); s_da[tid] = 1e30f; }
        else           { s_ib[tid - 128] = invx[bn + (tid - 128)];   s_db[tid - 128] = 1e30f; }
    }
    __syncthreads();   // s_* visible to all waves (no K-loop barriers below)

    // ---- K loop: 16 iters of 64 k-bytes; 8 coalesced dwordx4 loads + 32 MFMA ----
    const int lrow = lane & 15;
    const int kq = lane >> 4;
    const unsigned char* aBase = A + (size_t)(bm + wm + lrow) * GK + 16 * kq;
    const unsigned char* bBase = B + (size_t)(bn + wn + lrow) * GK + 16 * kq;

    floatx4 acc[4][4] = {};
    #pragma unroll 2
    for (int k0 = 0; k0 < GK; k0 += 64) {
        longx2 bf[4];
        #pragma unroll
        for (int u = 0; u < 4; ++u)
            bf[u] = *(const longx2*)(bBase + (size_t)u * (16 * GK) + k0);
        #pragma unroll
        for (int t = 0; t < 4; ++t) {
            longx2 af = *(const longx2*)(aBase + (size_t)t * (16 * GK) + k0);
            #pragma unroll
            for (int u = 0; u < 4; ++u) {
                acc[t][u] = __builtin_amdgcn_mfma_f32_16x16x32_fp8_fp8(
                    af[0], bf[u][0], acc[t][u], 0, 0, 0);
                acc[t][u] = __builtin_amdgcn_mfma_f32_16x16x32_fp8_fp8(
                    af[1], bf[u][1], acc[t][u], 0, 0, 0);
            }
        }
    }

    // ---- unified epilogue (C/D: col=lane&15, row=(lane>>4)*4+reg) ----
    const int cn = lane & 15, rq = lane >> 4;
    float ib_c[4], db_c[4];
    #pragma unroll
    for (int u = 0; u < 4; ++u) {
        int cl = wn + u * 16 + cn;
        ib_c[u] = s_ib[cl];
        db_c[u] = s_db[cl];
    }

    float csum[4] = {}, ccnt[4] = {};
    float my_rs = 0.f, my_rc = 0.f;
    #pragma unroll
    for (int t = 0; t < 4; ++t) {
        #pragma unroll
        for (int r = 0; r < 4; ++r) {
            const int rl = wm + t * 16 + rq * 4 + r;
            const float ia = s_ia[rl];
            const float da = s_da[rl];
            const int grow = bm + rl;
            float v = 0.f, w = 0.f;
            #pragma unroll
            for (int u = 0; u < 4; ++u) {
                const float s = acc[t][u][r];
                const int gcol = bn + wn + u * 16 + cn;
                const bool diag = (grow == gcol);
                float e = __expf(s * ia * ib_c[u]);
                if (fix_diag && diag) e = 1.0f;      // intra: diag logit -> 0
                v += e;
                csum[u] += e;
                w += (!diag && s > da) ? 1.f : 0.f;
                ccnt[u] += (!diag && s > db_c[u]) ? 1.f : 0.f;
            }
            v += __shfl_xor(v, 1); v += __shfl_xor(v, 2);
            v += __shfl_xor(v, 4); v += __shfl_xor(v, 8);
            w += __shfl_xor(w, 1); w += __shfl_xor(w, 2);
            w += __shfl_xor(w, 4); w += __shfl_xor(w, 8);
            if (cn == ((t << 2) | r)) { my_rs = v; my_rc = w; }
        }
    }
    // each lane owns one row of its wm-strip; two waves share each wm
    const int rl_local = wm + (cn >> 2) * 16 + rq * 4 + (cn & 3);
    redRS[rl_local][wave & 1] = my_rs;
    redRC[rl_local][wave & 1] = my_rc;

    float my_cs = 0.f, my_cc = 0.f;
    #pragma unroll
    for (int u = 0; u < 4; ++u) {
        float v = csum[u];
        v += __shfl_xor(v, 16); v += __shfl_xor(v, 32);
        float w = ccnt[u];
        w += __shfl_xor(w, 16); w += __shfl_xor(w, 32);
        if (rq == u) { my_cs = v; my_cc = w; }
    }
    const int cl_local = wn + rq * 16 + cn;
    redCS[cl_local][wave >> 1] = my_cs;
    redCC[cl_local][wave >> 1] = my_cc;
    __syncthreads();

    if (tid < 128) {
        atomicAdd(&srow[bm + tid], redRS[tid][0] + redRS[tid][1]);
        atomicAdd(&crow[bm + tid], redRC[tid][0] + redRC[tid][1]);
    } else if (do_cols) {
        const int t2 = tid - 128;
        atomicAdd(&scol[bn + t2], redCS[t2][0] + redCS[t2][1]);
        atomicAdd(&ccol[bn + t2], redCC[t2][0] + redCC[t2][1]);
    }
}

// Final per-row loss assembly + global sum
__global__ __launch_bounds__(256)
void final_loss(const float* __restrict__ sum_post, const float* __restrict__ cnt_post,
                const float* __restrict__ sum_brand, const float* __restrict__ cnt_brand,
                const float* __restrict__ dvec,
                const float* __restrict__ inv_post, const float* __restrict__ inv_brand,
                float* __restrict__ out) {
    const int i = blockIdx.x * 256 + threadIdx.x;
    float dl = dvec[i] * inv_post[i] * inv_brand[i] * INVT;
    float lp = logf(sum_post[i]);
    float lb = logf(sum_brand[i]);
    float rp = 1.0f / (4096.0f - cnt_post[i]) + 1.0f;
    float rb = 1.0f / (4096.0f - cnt_brand[i]) + 1.0f;
    float loss = 0.5f * (rb * (lb - dl) + rp * (lp - dl));
    #pragma unroll
    for (int off = 32; off > 0; off >>= 1) loss += __shfl_down(loss, off);
    __shared__ float sw[4];
    int wave = threadIdx.x >> 6, lane = threadIdx.x & 63;
    if (lane == 0) sw[wave] = loss;
    __syncthreads();
    if (threadIdx.x == 0) atomicAdd(out, sw[0] + sw[1] + sw[2] + sw[3]);
}

extern "C" void kernel_launch(void* const* d_in, const int* in_sizes, int n_in,
                              void* d_out, int out_size, void* d_ws, size_t ws_size,
                              hipStream_t stream) {
    const float* brand = (const float*)d_in[0];
    const float* post  = (const float*)d_in[1];
    float* out = (float*)d_out;

    char* ws = (char*)d_ws;
    unsigned char* postq  = (unsigned char*)ws;                          // 4 MB
    unsigned char* brandq = postq + (size_t)GN * GK;                     // 4 MB
    float* inv_post  = (float*)(brandq + (size_t)GN * GK);
    float* inv_brand = inv_post + GN;
    float* dvec      = inv_brand + GN;
    float* accs      = dvec + GN;        // [sum_post, sum_brand, cnt_post, cnt_brand]
    float* sum_post  = accs;
    float* sum_brand = accs + GN;
    float* cnt_post  = accs + 2 * GN;
    float* cnt_brand = accs + 3 * GN;
    float* cnt_dummy = accs + 4 * GN;    // intra count sink (never read)

    hipMemsetAsync(d_out, 0, sizeof(float) * out_size, stream);
    hipMemsetAsync(accs, 0, sizeof(float) * 4 * GN, stream);

    prep_all<<<GN, 256, 0, stream>>>(brand, post, brandq, postq,
                                     inv_brand, inv_post, dvec);
    gemm_all<<<NCROSS + 2 * NTILES, 256, 0, stream>>>(postq, brandq, dvec,
                                                      inv_post, inv_brand,
                                                      sum_post, cnt_post,
                                                      sum_brand, cnt_brand, cnt_dummy);
    final_loss<<<GN / 256, 256, 0, stream>>>(sum_post, cnt_post, sum_brand, cnt_brand,
                                             dvec, inv_post, inv_brand, out);
}

// Round 9
// 164.410 us; speedup vs baseline: 1.3209x; 1.3209x over previous
//
#include <hip/hip_runtime.h>

typedef float floatx4 __attribute__((ext_vector_type(4)));

#define GN 4096
#define GK 1024
#define BM 128
#define BN 128
#define BK 128          // K-bytes per LDS tile row -> 8 K-iters, 16 barriers total
#define INVT (1.0f/0.03f)
#define NTILES 528      // 32*33/2 upper-tri tiles per modality
#define NCROSS 1024     // 32*32 cross tiles

// OCP e4m3 byte -> f32 (inputs are satfinite converts of N(0,1); no NaN)
static __device__ __forceinline__ float fp8dec(unsigned b) {
    unsigned s = (b >> 7) & 1u, e = (b >> 3) & 0xFu, m = b & 7u;
    float v;
    if (e == 0) v = (float)m * 0.001953125f;                       // m * 2^-9
    else v = __builtin_bit_cast(float, ((e + 120u) << 23) | (m << 20));
    return s ? -v : v;
}

// One block per index i: quantize post-row i AND brand-row i, both inv-norms
// and the cross-diag dot in a single pass. (verified R7, absmax 0.0)
__global__ __launch_bounds__(256)
void prep_all(const float* __restrict__ brand, const float* __restrict__ post,
              unsigned char* __restrict__ brandq, unsigned char* __restrict__ postq,
              float* __restrict__ inv_brand, float* __restrict__ inv_post,
              float* __restrict__ dvec) {
    const int i = blockIdx.x, tid = threadIdx.x;
    const int wave = tid >> 6, lane = tid & 63;
    __shared__ float swp[4], swb[4], swd[4];

    float4 pv = ((const float4*)(post  + (size_t)i * GK))[tid];
    float4 bv = ((const float4*)(brand + (size_t)i * GK))[tid];
    int p = __builtin_amdgcn_cvt_pk_fp8_f32(pv.x, pv.y, 0, false);
    p = __builtin_amdgcn_cvt_pk_fp8_f32(pv.z, pv.w, p, true);
    int q = __builtin_amdgcn_cvt_pk_fp8_f32(bv.x, bv.y, 0, false);
    q = __builtin_amdgcn_cvt_pk_fp8_f32(bv.z, bv.w, q, true);
    ((int*)(postq  + (size_t)i * GK))[tid] = p;
    ((int*)(brandq + (size_t)i * GK))[tid] = q;

    float p0 = fp8dec(p & 0xFF), p1 = fp8dec((p >> 8) & 0xFF);
    float p2 = fp8dec((p >> 16) & 0xFF), p3 = fp8dec((p >> 24) & 0xFF);
    float b0 = fp8dec(q & 0xFF), b1 = fp8dec((q >> 8) & 0xFF);
    float b2 = fp8dec((q >> 16) & 0xFF), b3 = fp8dec((q >> 24) & 0xFF);
    float ssp = p0 * p0 + p1 * p1 + p2 * p2 + p3 * p3;
    float ssb = b0 * b0 + b1 * b1 + b2 * b2 + b3 * b3;
    float ssd = p0 * b0 + p1 * b1 + p2 * b2 + p3 * b3;
    #pragma unroll
    for (int off = 32; off > 0; off >>= 1) {
        ssp += __shfl_down(ssp, off);
        ssb += __shfl_down(ssb, off);
        ssd += __shfl_down(ssd, off);
    }
    if (lane == 0) { swp[wave] = ssp; swb[wave] = ssb; swd[wave] = ssd; }
    __syncthreads();
    if (tid == 0) {
        inv_post[i]  = 1.0f / sqrtf(swp[0] + swp[1] + swp[2] + swp[3]);
        inv_brand[i] = 1.0f / sqrtf(swb[0] + swb[1] + swb[2] + swb[3]);
        dvec[i]      = swd[0] + swd[1] + swd[2] + swd[3];
    }
}

// Unified GEMM dispatch, fp8 e4m3 16x16x32. LDS-staged, BK=128 B, 8 K-iters.
// LDS rows = 128 B = 8 chunks of 16 B; chunk c of row r at slot c^(r&7)
// (phase-conflict-free for both the DMA writes and the b128 fragment reads).
// k-permutation: each 16-B chunk feeds two MFMAs (low/high 8 B) — same
// permutation on A and B, so the accumulated dot product is unchanged.
__global__ __launch_bounds__(256)
void gemm_all(const unsigned char* __restrict__ postq, const unsigned char* __restrict__ brandq,
              const float* __restrict__ dvec,
              const float* __restrict__ inv_post, const float* __restrict__ inv_brand,
              float* __restrict__ sum_post, float* __restrict__ cnt_post,
              float* __restrict__ sum_brand, float* __restrict__ cnt_brand,
              float* __restrict__ cnt_dummy) {
    __shared__ __align__(16) unsigned char smem[2 * BM * BK];   // 32 KB tiles; epilogue red alias
    __shared__ float s_ia[128], s_ib[128], s_da[128], s_db[128];
    unsigned char* As = smem;
    unsigned char* Bs = smem + BM * BK;

    const int tid = threadIdx.x;
    const int wave = tid >> 6, lane = tid & 63;
    const int wm = (wave >> 1) * 64, wn = (wave & 1) * 64;

    int idx = blockIdx.x;
    const unsigned char *A, *B;
    float *srow, *scol, *crow, *ccol;
    int bm, bn;
    bool fix_diag, do_cols;

    if (idx < NCROSS) {
        fix_diag = false; do_cols = true;
        bm = (idx >> 5) * BM; bn = (idx & 31) * BN;
        A = postq; B = brandq;
        srow = sum_post; crow = cnt_post; scol = sum_brand; ccol = cnt_brand;
        if (tid < 128) { s_ia[tid] = inv_post[bm + tid] * INVT; s_da[tid] = dvec[bm + tid]; }
        else { int t2 = tid - 128; s_ib[t2] = inv_brand[bn + t2]; s_db[t2] = dvec[bn + t2]; }
    } else {
        fix_diag = true;
        idx -= NCROSS;
        const unsigned char* X; const float* invx; float* sacc;
        if (idx >= NTILES) { idx -= NTILES; X = brandq; invx = inv_brand; sacc = sum_brand; }
        else               {               X = postq;  invx = inv_post;  sacc = sum_post;  }
        int J = (int)((sqrtf(8.f * idx + 1.f) - 1.f) * 0.5f);
        while ((J + 1) * (J + 2) / 2 <= idx) ++J;
        while (J * (J + 1) / 2 > idx) --J;
        const int I = idx - J * (J + 1) / 2;
        bm = I * BM; bn = J * BN;
        A = X; B = X;
        srow = sacc; scol = sacc; crow = cnt_dummy; ccol = cnt_dummy;
        do_cols = (I != J);
        // sentinel diag: counts compare s > 1e30 -> always 0
        if (tid < 128) { s_ia[tid] = invx[bm + tid] * (0.8f * INVT); s_da[tid] = 1e30f; }
        else           { s_ib[tid - 128] = invx[bn + (tid - 128)];   s_db[tid - 128] = 1e30f; }
    }
    // s_* writes covered by the first __syncthreads in the K-loop.

    const int lrow = lane & 15;
    const int kq = lane >> 4;                 // 0..3

    // DMA: lane l -> strip row l>>3, LDS slot l&7, global chunk (l&7)^((l>>3)&7).
    // Per wave per iter: 4 A-instr + 4 B-instr, each staging 8 rows (1 KB).
    const size_t dma_off = (size_t)(lane >> 3) * GK + (((lane & 7) ^ ((lane >> 3) & 7)) * 16);
    const unsigned char* aSrc = A + (size_t)(bm + wave * 32) * GK + dma_off;
    const unsigned char* bSrc = B + (size_t)(bn + wave * 32) * GK + dma_off;
    unsigned char* aDst = As + (wave * 32) * BK;
    unsigned char* bDst = Bs + (wave * 32) * BK;

    floatx4 acc[4][4] = {};
    #pragma unroll 1
    for (int k0 = 0; k0 < GK; k0 += BK) {
        #pragma unroll
        for (int s = 0; s < 4; ++s) {
            __builtin_amdgcn_global_load_lds(
                (const __attribute__((address_space(1))) void*)(aSrc + (size_t)s * 8 * GK + k0),
                (__attribute__((address_space(3))) void*)(aDst + s * 8 * BK), 16, 0, 0);
            __builtin_amdgcn_global_load_lds(
                (const __attribute__((address_space(1))) void*)(bSrc + (size_t)s * 8 * GK + k0),
                (__attribute__((address_space(3))) void*)(bDst + s * 8 * BK), 16, 0, 0);
        }
        __syncthreads();

        #pragma unroll
        for (int h = 0; h < 2; ++h) {
            long2 bfr[4];
            #pragma unroll
            for (int u = 0; u < 4; ++u) {
                const int m = wn + u * 16 + lrow;
                bfr[u] = *(const long2*)(Bs + m * BK + (((4 * h + kq) ^ (lrow & 7)) * 16));
            }
            #pragma unroll
            for (int t = 0; t < 4; ++t) {
                const int m = wm + t * 16 + lrow;
                const long2 af = *(const long2*)(As + m * BK + (((4 * h + kq) ^ (lrow & 7)) * 16));
                #pragma unroll
                for (int u = 0; u < 4; ++u) {
                    acc[t][u] = __builtin_amdgcn_mfma_f32_16x16x32_fp8_fp8(
                        af.x, bfr[u].x, acc[t][u], 0, 0, 0);
                    acc[t][u] = __builtin_amdgcn_mfma_f32_16x16x32_fp8_fp8(
                        af.y, bfr[u].y, acc[t][u], 0, 0, 0);
                }
            }
        }
        __syncthreads();   // also separates last tile reads from epilogue red alias
    }

    // ---- unified epilogue (C/D: col=lane&15, row=(lane>>4)*4+reg) ----
    const int cn = lane & 15, rq = lane >> 4;
    float ib_c[4], db_c[4];
    #pragma unroll
    for (int u = 0; u < 4; ++u) {
        int cl = wn + u * 16 + cn;
        ib_c[u] = s_ib[cl];
        db_c[u] = s_db[cl];
    }

    float csum[4] = {}, ccnt[4] = {};
    float my_rs = 0.f, my_rc = 0.f;
    #pragma unroll
    for (int t = 0; t < 4; ++t) {
        #pragma unroll
        for (int r = 0; r < 4; ++r) {
            const int rl = wm + t * 16 + rq * 4 + r;
            const float ia = s_ia[rl];
            const float da = s_da[rl];
            const int grow = bm + rl;
            float v = 0.f, w = 0.f;
            #pragma unroll
            for (int u = 0; u < 4; ++u) {
                const float s = acc[t][u][r];
                const int gcol = bn + wn + u * 16 + cn;
                const bool diag = (grow == gcol);
                float e = __expf(s * ia * ib_c[u]);
                if (fix_diag && diag) e = 1.0f;      // intra: diag logit -> 0
                v += e;
                csum[u] += e;
                w += (!diag && s > da) ? 1.f : 0.f;
                ccnt[u] += (!diag && s > db_c[u]) ? 1.f : 0.f;
            }
            v += __shfl_xor(v, 1); v += __shfl_xor(v, 2);
            v += __shfl_xor(v, 4); v += __shfl_xor(v, 8);
            w += __shfl_xor(w, 1); w += __shfl_xor(w, 2);
            w += __shfl_xor(w, 4); w += __shfl_xor(w, 8);
            if (cn == ((t << 2) | r)) { my_rs = v; my_rc = w; }
        }
    }

    // reduction scratch aliases the (dead) tile LDS
    float (*redRS)[2] = (float(*)[2])(smem);
    float (*redRC)[2] = (float(*)[2])(smem + 1024);
    float (*redCS)[2] = (float(*)[2])(smem + 2048);
    float (*redCC)[2] = (float(*)[2])(smem + 3072);

    const int rl_local = wm + (cn >> 2) * 16 + rq * 4 + (cn & 3);
    redRS[rl_local][wave & 1] = my_rs;
    redRC[rl_local][wave & 1] = my_rc;

    float my_cs = 0.f, my_cc = 0.f;
    #pragma unroll
    for (int u = 0; u < 4; ++u) {
        float v = csum[u];
        v += __shfl_xor(v, 16); v += __shfl_xor(v, 32);
        float w = ccnt[u];
        w += __shfl_xor(w, 16); w += __shfl_xor(w, 32);
        if (rq == u) { my_cs = v; my_cc = w; }
    }
    const int cl_local = wn + rq * 16 + cn;
    redCS[cl_local][wave >> 1] = my_cs;
    redCC[cl_local][wave >> 1] = my_cc;
    __syncthreads();

    if (tid < 128) {
        atomicAdd(&srow[bm + tid], redRS[tid][0] + redRS[tid][1]);
        atomicAdd(&crow[bm + tid], redRC[tid][0] + redRC[tid][1]);
    } else if (do_cols) {
        const int t2 = tid - 128;
        atomicAdd(&scol[bn + t2], redCS[t2][0] + redCS[t2][1]);
        atomicAdd(&ccol[bn + t2], redCC[t2][0] + redCC[t2][1]);
    }
}

// Final per-row loss assembly + global sum
__global__ __launch_bounds__(256)
void final_loss(const float* __restrict__ sum_post, const float* __restrict__ cnt_post,
                const float* __restrict__ sum_brand, const float* __restrict__ cnt_brand,
                const float* __restrict__ dvec,
                const float* __restrict__ inv_post, const float* __restrict__ inv_brand,
                float* __restrict__ out) {
    const int i = blockIdx.x * 256 + threadIdx.x;
    float dl = dvec[i] * inv_post[i] * inv_brand[i] * INVT;
    float lp = logf(sum_post[i]);
    float lb = logf(sum_brand[i]);
    float rp = 1.0f / (4096.0f - cnt_post[i]) + 1.0f;
    float rb = 1.0f / (4096.0f - cnt_brand[i]) + 1.0f;
    float loss = 0.5f * (rb * (lb - dl) + rp * (lp - dl));
    #pragma unroll
    for (int off = 32; off > 0; off >>= 1) loss += __shfl_down(loss, off);
    __shared__ float sw[4];
    int wave = threadIdx.x >> 6, lane = threadIdx.x & 63;
    if (lane == 0) sw[wave] = loss;
    __syncthreads();
    if (threadIdx.x == 0) atomicAdd(out, sw[0] + sw[1] + sw[2] + sw[3]);
}

extern "C" void kernel_launch(void* const* d_in, const int* in_sizes, int n_in,
                              void* d_out, int out_size, void* d_ws, size_t ws_size,
                              hipStream_t stream) {
    const float* brand = (const float*)d_in[0];
    const float* post  = (const float*)d_in[1];
    float* out = (float*)d_out;

    char* ws = (char*)d_ws;
    unsigned char* postq  = (unsigned char*)ws;                          // 4 MB
    unsigned char* brandq = postq + (size_t)GN * GK;                     // 4 MB
    float* inv_post  = (float*)(brandq + (size_t)GN * GK);
    float* inv_brand = inv_post + GN;
    float* dvec      = inv_brand + GN;
    float* accs      = dvec + GN;        // [sum_post, sum_brand, cnt_post, cnt_brand]
    float* sum_post  = accs;
    float* sum_brand = accs + GN;
    float* cnt_post  = accs + 2 * GN;
    float* cnt_brand = accs + 3 * GN;
    float* cnt_dummy = accs + 4 * GN;    // intra count sink (never read)

    hipMemsetAsync(d_out, 0, sizeof(float) * out_size, stream);
    hipMemsetAsync(accs, 0, sizeof(float) * 4 * GN, stream);

    prep_all<<<GN, 256, 0, stream>>>(brand, post, brandq, postq,
                                     inv_brand, inv_post, dvec);
    gemm_all<<<NCROSS + 2 * NTILES, 256, 0, stream>>>(postq, brandq, dvec,
                                                      inv_post, inv_brand,
                                                      sum_post, cnt_post,
                                                      sum_brand, cnt_brand, cnt_dummy);
    final_loss<<<GN / 256, 256, 0, stream>>>(sum_post, cnt_post, sum_brand, cnt_brand,
                                             dvec, inv_post, inv_brand, out);
}

// Round 10
// 146.307 us; speedup vs baseline: 1.4843x; 1.1237x over previous
//
#include <hip/hip_runtime.h>

typedef float floatx4 __attribute__((ext_vector_type(4)));

#define GN 4096
#define GK 1024
#define BM 128
#define BN 128
#define BK 128          // K-bytes per LDS tile row -> 8 K-iters, 16 barriers
#define INVT (1.0f/0.03f)
#define NTILES 528      // 32*33/2 upper-tri tiles per modality
#define NCROSS 1024     // 32*32 cross tiles

// OCP e4m3 byte -> f32 (inputs are satfinite converts of N(0,1); no NaN)
static __device__ __forceinline__ float fp8dec(unsigned b) {
    unsigned s = (b >> 7) & 1u, e = (b >> 3) & 0xFu, m = b & 7u;
    float v;
    if (e == 0) v = (float)m * 0.001953125f;                       // m * 2^-9
    else v = __builtin_bit_cast(float, ((e + 120u) << 23) | (m << 20));
    return s ? -v : v;
}

// One block per index i: quantize post-row i AND brand-row i, both inv-norms
// and the cross-diag dot in a single pass. Also zeroes the accumulators
// (replaces the hipMemsetAsync dispatches).
__global__ __launch_bounds__(256)
void prep_all(const float* __restrict__ brand, const float* __restrict__ post,
              unsigned char* __restrict__ brandq, unsigned char* __restrict__ postq,
              float* __restrict__ inv_brand, float* __restrict__ inv_post,
              float* __restrict__ dvec, float* __restrict__ accs,
              float* __restrict__ out) {
    const int i = blockIdx.x, tid = threadIdx.x;
    const int wave = tid >> 6, lane = tid & 63;
    __shared__ float swp[4], swb[4], swd[4];

    float4 pv = ((const float4*)(post  + (size_t)i * GK))[tid];
    float4 bv = ((const float4*)(brand + (size_t)i * GK))[tid];
    int p = __builtin_amdgcn_cvt_pk_fp8_f32(pv.x, pv.y, 0, false);
    p = __builtin_amdgcn_cvt_pk_fp8_f32(pv.z, pv.w, p, true);
    int q = __builtin_amdgcn_cvt_pk_fp8_f32(bv.x, bv.y, 0, false);
    q = __builtin_amdgcn_cvt_pk_fp8_f32(bv.z, bv.w, q, true);
    ((int*)(postq  + (size_t)i * GK))[tid] = p;
    ((int*)(brandq + (size_t)i * GK))[tid] = q;

    float p0 = fp8dec(p & 0xFF), p1 = fp8dec((p >> 8) & 0xFF);
    float p2 = fp8dec((p >> 16) & 0xFF), p3 = fp8dec((p >> 24) & 0xFF);
    float b0 = fp8dec(q & 0xFF), b1 = fp8dec((q >> 8) & 0xFF);
    float b2 = fp8dec((q >> 16) & 0xFF), b3 = fp8dec((q >> 24) & 0xFF);
    float ssp = p0 * p0 + p1 * p1 + p2 * p2 + p3 * p3;
    float ssb = b0 * b0 + b1 * b1 + b2 * b2 + b3 * b3;
    float ssd = p0 * b0 + p1 * b1 + p2 * b2 + p3 * b3;
    #pragma unroll
    for (int off = 32; off > 0; off >>= 1) {
        ssp += __shfl_down(ssp, off);
        ssb += __shfl_down(ssb, off);
        ssd += __shfl_down(ssd, off);
    }
    if (lane == 0) { swp[wave] = ssp; swb[wave] = ssb; swd[wave] = ssd; }
    __syncthreads();
    if (tid == 0) {
        inv_post[i]  = 1.0f / sqrtf(swp[0] + swp[1] + swp[2] + swp[3]);
        inv_brand[i] = 1.0f / sqrtf(swb[0] + swb[1] + swb[2] + swb[3]);
        dvec[i]      = swd[0] + swd[1] + swd[2] + swd[3];
    } else if (tid == 64) {
        accs[i] = 0.f; accs[GN + i] = 0.f; accs[2 * GN + i] = 0.f; accs[3 * GN + i] = 0.f;
        if (i == 0) out[0] = 0.f;
    }
}

// Unified GEMM dispatch, fp8 e4m3 16x16x32. LDS-staged, BK=128 B, 8 K-iters.
// LDS = tile buffers ONLY (32768 B) -> 5 blocks/CU; launch_bounds forces
// VGPR <= 102 -> 5 waves/SIMD. Per-row/col scalars (inv norms, diag dots)
// are read from L2-resident global arrays in the epilogue.
// LDS rows = 128 B = 8 chunks of 16 B; chunk c of row r at slot c^(r&7)
// (phase-conflict-free for DMA writes and b128 fragment reads).
// k-permutation: each 16-B chunk feeds two MFMAs (low/high 8 B) — same
// permutation on A and B, so the accumulated dot product is unchanged.
__global__ __launch_bounds__(256, 5)
void gemm_all(const unsigned char* __restrict__ postq, const unsigned char* __restrict__ brandq,
              const float* __restrict__ dvec,
              const float* __restrict__ inv_post, const float* __restrict__ inv_brand,
              float* __restrict__ sum_post, float* __restrict__ cnt_post,
              float* __restrict__ sum_brand, float* __restrict__ cnt_brand) {
    __shared__ __align__(16) unsigned char smem[2 * BM * BK];   // 32 KB; epilogue red alias
    unsigned char* As = smem;
    unsigned char* Bs = smem + BM * BK;

    const int tid = threadIdx.x;
    const int wave = tid >> 6, lane = tid & 63;
    const int wm = (wave >> 1) * 64, wn = (wave & 1) * 64;

    int idx = blockIdx.x;
    const unsigned char *A, *B;
    const float *invA, *invB;
    float *srow, *scol, *crow, *ccol;
    int bm, bn;
    float iaScale;
    bool is_cross, do_cols;

    if (idx < NCROSS) {
        is_cross = true; do_cols = true;
        bm = (idx >> 5) * BM; bn = (idx & 31) * BN;
        A = postq; B = brandq;
        invA = inv_post; invB = inv_brand; iaScale = INVT;
        srow = sum_post; crow = cnt_post; scol = sum_brand; ccol = cnt_brand;
    } else {
        is_cross = false;
        idx -= NCROSS;
        const unsigned char* X; const float* invx; float* sacc;
        if (idx >= NTILES) { idx -= NTILES; X = brandq; invx = inv_brand; sacc = sum_brand; }
        else               {               X = postq;  invx = inv_post;  sacc = sum_post;  }
        int J = (int)((sqrtf(8.f * idx + 1.f) - 1.f) * 0.5f);
        while ((J + 1) * (J + 2) / 2 <= idx) ++J;
        while (J * (J + 1) / 2 > idx) --J;
        const int I = idx - J * (J + 1) / 2;
        bm = I * BM; bn = J * BN;
        A = X; B = X;
        invA = invx; invB = invx; iaScale = 0.8f * INVT;
        srow = sacc; scol = sacc; crow = nullptr; ccol = nullptr;
        do_cols = (I != J);
    }

    const int lrow = lane & 15;
    const int kq = lane >> 4;                 // 0..3

    // DMA: lane l -> strip row l>>3, LDS slot l&7, global chunk (l&7)^((l>>3)&7).
    // Per wave per iter: 4 A-instr + 4 B-instr, each staging 8 rows (1 KB).
    const size_t dma_off = (size_t)(lane >> 3) * GK + (((lane & 7) ^ ((lane >> 3) & 7)) * 16);
    const unsigned char* aSrc = A + (size_t)(bm + wave * 32) * GK + dma_off;
    const unsigned char* bSrc = B + (size_t)(bn + wave * 32) * GK + dma_off;
    unsigned char* aDst = As + (wave * 32) * BK;
    unsigned char* bDst = Bs + (wave * 32) * BK;

    floatx4 acc[4][4] = {};
    #pragma unroll 1
    for (int k0 = 0; k0 < GK; k0 += BK) {
        #pragma unroll
        for (int s = 0; s < 4; ++s) {
            __builtin_amdgcn_global_load_lds(
                (const __attribute__((address_space(1))) void*)(aSrc + (size_t)s * 8 * GK + k0),
                (__attribute__((address_space(3))) void*)(aDst + s * 8 * BK), 16, 0, 0);
            __builtin_amdgcn_global_load_lds(
                (const __attribute__((address_space(1))) void*)(bSrc + (size_t)s * 8 * GK + k0),
                (__attribute__((address_space(3))) void*)(bDst + s * 8 * BK), 16, 0, 0);
        }
        __syncthreads();

        #pragma unroll
        for (int h = 0; h < 2; ++h) {
            long2 bfr[4];
            #pragma unroll
            for (int u = 0; u < 4; ++u) {
                const int m = wn + u * 16 + lrow;
                bfr[u] = *(const long2*)(Bs + m * BK + (((4 * h + kq) ^ (lrow & 7)) * 16));
            }
            #pragma unroll
            for (int t = 0; t < 4; ++t) {
                const int m = wm + t * 16 + lrow;
                const long2 af = *(const long2*)(As + m * BK + (((4 * h + kq) ^ (lrow & 7)) * 16));
                #pragma unroll
                for (int u = 0; u < 4; ++u) {
                    acc[t][u] = __builtin_amdgcn_mfma_f32_16x16x32_fp8_fp8(
                        af.x, bfr[u].x, acc[t][u], 0, 0, 0);
                    acc[t][u] = __builtin_amdgcn_mfma_f32_16x16x32_fp8_fp8(
                        af.y, bfr[u].y, acc[t][u], 0, 0, 0);
                }
            }
        }
        __syncthreads();   // also separates last tile reads from epilogue red alias
    }

    // ---- epilogue (C/D: col=lane&15, row=(lane>>4)*4+reg) ----
    const int cn = lane & 15, rq = lane >> 4;
    float ib_c[4], db_c[4];
    #pragma unroll
    for (int u = 0; u < 4; ++u) {
        const int gc = bn + wn + u * 16 + cn;
        ib_c[u] = invB[gc];
        db_c[u] = is_cross ? dvec[gc] : 0.f;
    }

    float csum[4] = {}, ccnt[4] = {};
    float my_rs = 0.f, my_rc = 0.f;
    #pragma unroll
    for (int t = 0; t < 4; ++t) {
        #pragma unroll
        for (int r = 0; r < 4; ++r) {
            const int rl = wm + t * 16 + rq * 4 + r;
            const int grow = bm + rl;
            const float ia = invA[grow] * iaScale;
            float v = 0.f, w = 0.f;
            if (is_cross) {
                const float da = dvec[grow];
                #pragma unroll
                for (int u = 0; u < 4; ++u) {
                    const float s = acc[t][u][r];
                    const int gcol = bn + wn + u * 16 + cn;
                    const bool diag = (grow == gcol);
                    float e = __expf(s * ia * ib_c[u]);
                    v += e;
                    csum[u] += e;
                    w += (!diag && s > da) ? 1.f : 0.f;
                    ccnt[u] += (!diag && s > db_c[u]) ? 1.f : 0.f;
                }
                w += __shfl_xor(w, 1); w += __shfl_xor(w, 2);
                w += __shfl_xor(w, 4); w += __shfl_xor(w, 8);
            } else {
                #pragma unroll
                for (int u = 0; u < 4; ++u) {
                    const float s = acc[t][u][r];
                    const int gcol = bn + wn + u * 16 + cn;
                    float e = (grow == gcol) ? 1.0f : __expf(s * ia * ib_c[u]);
                    v += e;
                    csum[u] += e;
                }
            }
            v += __shfl_xor(v, 1); v += __shfl_xor(v, 2);
            v += __shfl_xor(v, 4); v += __shfl_xor(v, 8);
            if (cn == ((t << 2) | r)) { my_rs = v; my_rc = w; }
        }
    }

    // reduction scratch aliases the (dead) tile LDS
    float (*redRS)[2] = (float(*)[2])(smem);
    float (*redRC)[2] = (float(*)[2])(smem + 1024);
    float (*redCS)[2] = (float(*)[2])(smem + 2048);
    float (*redCC)[2] = (float(*)[2])(smem + 3072);

    const int rl_local = wm + (cn >> 2) * 16 + rq * 4 + (cn & 3);
    redRS[rl_local][wave & 1] = my_rs;
    redRC[rl_local][wave & 1] = my_rc;

    float my_cs = 0.f, my_cc = 0.f;
    #pragma unroll
    for (int u = 0; u < 4; ++u) {
        float v = csum[u];
        v += __shfl_xor(v, 16); v += __shfl_xor(v, 32);
        if (rq == u) my_cs = v;
        if (is_cross) {
            float w = ccnt[u];
            w += __shfl_xor(w, 16); w += __shfl_xor(w, 32);
            if (rq == u) my_cc = w;
        }
    }
    const int cl_local = wn + rq * 16 + cn;
    redCS[cl_local][wave >> 1] = my_cs;
    redCC[cl_local][wave >> 1] = my_cc;
    __syncthreads();

    if (tid < 128) {
        atomicAdd(&srow[bm + tid], redRS[tid][0] + redRS[tid][1]);
        if (is_cross) atomicAdd(&crow[bm + tid], redRC[tid][0] + redRC[tid][1]);
    } else if (do_cols) {
        const int t2 = tid - 128;
        atomicAdd(&scol[bn + t2], redCS[t2][0] + redCS[t2][1]);
        if (is_cross) atomicAdd(&ccol[bn + t2], redCC[t2][0] + redCC[t2][1]);
    }
}

// Final per-row loss assembly + global sum
__global__ __launch_bounds__(256)
void final_loss(const float* __restrict__ sum_post, const float* __restrict__ cnt_post,
                const float* __restrict__ sum_brand, const float* __restrict__ cnt_brand,
                const float* __restrict__ dvec,
                const float* __restrict__ inv_post, const float* __restrict__ inv_brand,
                float* __restrict__ out) {
    const int i = blockIdx.x * 256 + threadIdx.x;
    float dl = dvec[i] * inv_post[i] * inv_brand[i] * INVT;
    float lp = logf(sum_post[i]);
    float lb = logf(sum_brand[i]);
    float rp = 1.0f / (4096.0f - cnt_post[i]) + 1.0f;
    float rb = 1.0f / (4096.0f - cnt_brand[i]) + 1.0f;
    float loss = 0.5f * (rb * (lb - dl) + rp * (lp - dl));
    #pragma unroll
    for (int off = 32; off > 0; off >>= 1) loss += __shfl_down(loss, off);
    __shared__ float sw[4];
    int wave = threadIdx.x >> 6, lane = threadIdx.x & 63;
    if (lane == 0) sw[wave] = loss;
    __syncthreads();
    if (threadIdx.x == 0) atomicAdd(out, sw[0] + sw[1] + sw[2] + sw[3]);
}

extern "C" void kernel_launch(void* const* d_in, const int* in_sizes, int n_in,
                              void* d_out, int out_size, void* d_ws, size_t ws_size,
                              hipStream_t stream) {
    const float* brand = (const float*)d_in[0];
    const float* post  = (const float*)d_in[1];
    float* out = (float*)d_out;

    char* ws = (char*)d_ws;
    unsigned char* postq  = (unsigned char*)ws;                          // 4 MB
    unsigned char* brandq = postq + (size_t)GN * GK;                     // 4 MB
    float* inv_post  = (float*)(brandq + (size_t)GN * GK);
    float* inv_brand = inv_post + GN;
    float* dvec      = inv_brand + GN;
    float* accs      = dvec + GN;        // [sum_post, sum_brand, cnt_post, cnt_brand]
    float* sum_post  = accs;
    float* sum_brand = accs + GN;
    float* cnt_post  = accs + 2 * GN;
    float* cnt_brand = accs + 3 * GN;

    prep_all<<<GN, 256, 0, stream>>>(brand, post, brandq, postq,
                                     inv_brand, inv_post, dvec, accs, out);
    gemm_all<<<NCROSS + 2 * NTILES, 256, 0, stream>>>(postq, brandq, dvec,
                                                      inv_post, inv_brand,
                                                      sum_post, cnt_post,
                                                      sum_brand, cnt_brand);
    final_loss<<<GN / 256, 256, 0, stream>>>(sum_post, cnt_post, sum_brand, cnt_brand,
                                             dvec, inv_post, inv_brand, out);
}

// Round 11
// 137.298 us; speedup vs baseline: 1.5817x; 1.0656x over previous
//
#include <hip/hip_runtime.h>

typedef float floatx4 __attribute__((ext_vector_type(4)));
typedef int intx4 __attribute__((ext_vector_type(4)));

#define GN 4096
#define GK 1024
#define BM 128
#define BN 128
#define BK 128          // K-bytes per LDS tile row -> 8 K-iters, 16 barriers
#define INVT (1.0f/0.03f)
#define QS 24.0f        // int8 quant scale; dots <= 1024*127^2 < 2^24 (fp32-exact)
#define NTILES 528      // 32*33/2 upper-tri tiles per modality
#define NCROSS 1024     // 32*32 cross tiles

static __device__ __forceinline__ int q8(float x) {
    int v = __float2int_rn(x * QS);
    return v < -127 ? -127 : (v > 127 ? 127 : v);
}

// One block per index i: int8-quantize post-row i AND brand-row i, both
// inv-norms (of quantized ints) and the cross-diag int dot, single pass.
// Also zeroes the accumulators + out (replaces hipMemsetAsync dispatches).
__global__ __launch_bounds__(256)
void prep_all(const float* __restrict__ brand, const float* __restrict__ post,
              unsigned char* __restrict__ brandq, unsigned char* __restrict__ postq,
              float* __restrict__ inv_brand, float* __restrict__ inv_post,
              float* __restrict__ dvec, float* __restrict__ accs,
              float* __restrict__ out) {
    const int i = blockIdx.x, tid = threadIdx.x;
    const int wave = tid >> 6, lane = tid & 63;
    __shared__ float swp[4], swb[4], swd[4];

    float4 pv = ((const float4*)(post  + (size_t)i * GK))[tid];
    float4 bv = ((const float4*)(brand + (size_t)i * GK))[tid];
    int p0 = q8(pv.x), p1 = q8(pv.y), p2 = q8(pv.z), p3 = q8(pv.w);
    int b0 = q8(bv.x), b1 = q8(bv.y), b2 = q8(bv.z), b3 = q8(bv.w);
    ((int*)(postq  + (size_t)i * GK))[tid] =
        (p0 & 255) | ((p1 & 255) << 8) | ((p2 & 255) << 16) | ((p3 & 255) << 24);
    ((int*)(brandq + (size_t)i * GK))[tid] =
        (b0 & 255) | ((b1 & 255) << 8) | ((b2 & 255) << 16) | ((b3 & 255) << 24);

    // per-thread int partials (<= 4*127^2), accumulated as exact-int floats
    float ssp = (float)(p0 * p0 + p1 * p1 + p2 * p2 + p3 * p3);
    float ssb = (float)(b0 * b0 + b1 * b1 + b2 * b2 + b3 * b3);
    float ssd = (float)(p0 * b0 + p1 * b1 + p2 * b2 + p3 * b3);
    #pragma unroll
    for (int off = 32; off > 0; off >>= 1) {
        ssp += __shfl_down(ssp, off);
        ssb += __shfl_down(ssb, off);
        ssd += __shfl_down(ssd, off);
    }
    if (lane == 0) { swp[wave] = ssp; swb[wave] = ssb; swd[wave] = ssd; }
    __syncthreads();
    if (tid == 0) {
        inv_post[i]  = 1.0f / sqrtf(swp[0] + swp[1] + swp[2] + swp[3]);
        inv_brand[i] = 1.0f / sqrtf(swb[0] + swb[1] + swb[2] + swb[3]);
        dvec[i]      = swd[0] + swd[1] + swd[2] + swd[3];
    } else if (tid == 64) {
        accs[i] = 0.f; accs[GN + i] = 0.f; accs[2 * GN + i] = 0.f; accs[3 * GN + i] = 0.f;
        if (i == 0) out[0] = 0.f;
    }
}

// Unified GEMM dispatch, int8 16x16x64 MFMA (2x fp8 rate, exact int scores).
// LDS-staged, BK=128 B, 8 K-iters; LDS = 32768 B -> 5 blocks/CU.
// LDS rows = 128 B = 8 chunks of 16 B; chunk c of row r at slot c^(r&7)
// (phase-conflict-free for DMA writes and b128 fragment reads).
// i8 fragment: lane (lrow,kq) holds 16 contiguous k-bytes at chunk 4h+kq of
// its row -> one dwordx4 read feeds one MFMA (K=64).
__global__ __launch_bounds__(256, 5)
void gemm_all(const unsigned char* __restrict__ postq, const unsigned char* __restrict__ brandq,
              const float* __restrict__ dvec,
              const float* __restrict__ inv_post, const float* __restrict__ inv_brand,
              float* __restrict__ sum_post, float* __restrict__ cnt_post,
              float* __restrict__ sum_brand, float* __restrict__ cnt_brand) {
    __shared__ __align__(16) unsigned char smem[2 * BM * BK];   // 32 KB; epilogue red alias
    unsigned char* As = smem;
    unsigned char* Bs = smem + BM * BK;

    const int tid = threadIdx.x;
    const int wave = tid >> 6, lane = tid & 63;
    const int wm = (wave >> 1) * 64, wn = (wave & 1) * 64;

    int idx = blockIdx.x;
    const unsigned char *A, *B;
    const float *invA, *invB;
    float *srow, *scol, *crow, *ccol;
    int bm, bn;
    float iaScale;
    bool is_cross, do_cols;

    if (idx < NCROSS) {
        is_cross = true; do_cols = true;
        bm = (idx >> 5) * BM; bn = (idx & 31) * BN;
        A = postq; B = brandq;
        invA = inv_post; invB = inv_brand; iaScale = INVT;
        srow = sum_post; crow = cnt_post; scol = sum_brand; ccol = cnt_brand;
    } else {
        is_cross = false;
        idx -= NCROSS;
        const unsigned char* X; const float* invx; float* sacc;
        if (idx >= NTILES) { idx -= NTILES; X = brandq; invx = inv_brand; sacc = sum_brand; }
        else               {               X = postq;  invx = inv_post;  sacc = sum_post;  }
        int J = (int)((sqrtf(8.f * idx + 1.f) - 1.f) * 0.5f);
        while ((J + 1) * (J + 2) / 2 <= idx) ++J;
        while (J * (J + 1) / 2 > idx) --J;
        const int I = idx - J * (J + 1) / 2;
        bm = I * BM; bn = J * BN;
        A = X; B = X;
        invA = invx; invB = invx; iaScale = 0.8f * INVT;
        srow = sacc; scol = sacc; crow = nullptr; ccol = nullptr;
        do_cols = (I != J);
    }

    const int lrow = lane & 15;
    const int kq = lane >> 4;                 // 0..3

    // DMA: lane l -> strip row l>>3, LDS slot l&7, global chunk (l&7)^((l>>3)&7).
    // Per wave per iter: 4 A-instr + 4 B-instr, each staging 8 rows (1 KB).
    const size_t dma_off = (size_t)(lane >> 3) * GK + (((lane & 7) ^ ((lane >> 3) & 7)) * 16);
    const unsigned char* aSrc = A + (size_t)(bm + wave * 32) * GK + dma_off;
    const unsigned char* bSrc = B + (size_t)(bn + wave * 32) * GK + dma_off;
    unsigned char* aDst = As + (wave * 32) * BK;
    unsigned char* bDst = Bs + (wave * 32) * BK;

    intx4 acc[4][4] = {};
    #pragma unroll 1
    for (int k0 = 0; k0 < GK; k0 += BK) {
        #pragma unroll
        for (int s = 0; s < 4; ++s) {
            __builtin_amdgcn_global_load_lds(
                (const __attribute__((address_space(1))) void*)(aSrc + (size_t)s * 8 * GK + k0),
                (__attribute__((address_space(3))) void*)(aDst + s * 8 * BK), 16, 0, 0);
            __builtin_amdgcn_global_load_lds(
                (const __attribute__((address_space(1))) void*)(bSrc + (size_t)s * 8 * GK + k0),
                (__attribute__((address_space(3))) void*)(bDst + s * 8 * BK), 16, 0, 0);
        }
        __syncthreads();

        #pragma unroll
        for (int h = 0; h < 2; ++h) {
            intx4 bfr[4];
            #pragma unroll
            for (int u = 0; u < 4; ++u) {
                const int m = wn + u * 16 + lrow;
                bfr[u] = *(const intx4*)(Bs + m * BK + (((4 * h + kq) ^ (m & 7)) * 16));
            }
            #pragma unroll
            for (int t = 0; t < 4; ++t) {
                const int m = wm + t * 16 + lrow;
                const intx4 af = *(const intx4*)(As + m * BK + (((4 * h + kq) ^ (m & 7)) * 16));
                #pragma unroll
                for (int u = 0; u < 4; ++u)
                    acc[t][u] = __builtin_amdgcn_mfma_i32_16x16x64_i8(
                        af, bfr[u], acc[t][u], 0, 0, 0);
            }
        }
        __syncthreads();   // also separates last tile reads from epilogue red alias
    }

    // ---- epilogue (C/D: col=lane&15, row=(lane>>4)*4+reg; shape-determined) ----
    const int cn = lane & 15, rq = lane >> 4;
    float ib_c[4], db_c[4];
    #pragma unroll
    for (int u = 0; u < 4; ++u) {
        const int gc = bn + wn + u * 16 + cn;
        ib_c[u] = invB[gc];
        db_c[u] = is_cross ? dvec[gc] : 0.f;
    }

    float csum[4] = {}, ccnt[4] = {};
    float my_rs = 0.f, my_rc = 0.f;
    #pragma unroll
    for (int t = 0; t < 4; ++t) {
        #pragma unroll
        for (int r = 0; r < 4; ++r) {
            const int rl = wm + t * 16 + rq * 4 + r;
            const int grow = bm + rl;
            const float ia = invA[grow] * iaScale;
            float v = 0.f, w = 0.f;
            if (is_cross) {
                const float da = dvec[grow];
                #pragma unroll
                for (int u = 0; u < 4; ++u) {
                    const float s = (float)acc[t][u][r];   // exact int < 2^24
                    const int gcol = bn + wn + u * 16 + cn;
                    const bool diag = (grow == gcol);
                    float e = __expf(s * ia * ib_c[u]);
                    v += e;
                    csum[u] += e;
                    w += (!diag && s > da) ? 1.f : 0.f;
                    ccnt[u] += (!diag && s > db_c[u]) ? 1.f : 0.f;
                }
                w += __shfl_xor(w, 1); w += __shfl_xor(w, 2);
                w += __shfl_xor(w, 4); w += __shfl_xor(w, 8);
            } else {
                #pragma unroll
                for (int u = 0; u < 4; ++u) {
                    const float s = (float)acc[t][u][r];
                    const int gcol = bn + wn + u * 16 + cn;
                    float e = (grow == gcol) ? 1.0f : __expf(s * ia * ib_c[u]);
                    v += e;
                    csum[u] += e;
                }
            }
            v += __shfl_xor(v, 1); v += __shfl_xor(v, 2);
            v += __shfl_xor(v, 4); v += __shfl_xor(v, 8);
            if (cn == ((t << 2) | r)) { my_rs = v; my_rc = w; }
        }
    }

    // reduction scratch aliases the (dead) tile LDS
    float (*redRS)[2] = (float(*)[2])(smem);
    float (*redRC)[2] = (float(*)[2])(smem + 1024);
    float (*redCS)[2] = (float(*)[2])(smem + 2048);
    float (*redCC)[2] = (float(*)[2])(smem + 3072);

    const int rl_local = wm + (cn >> 2) * 16 + rq * 4 + (cn & 3);
    redRS[rl_local][wave & 1] = my_rs;
    redRC[rl_local][wave & 1] = my_rc;

    float my_cs = 0.f, my_cc = 0.f;
    #pragma unroll
    for (int u = 0; u < 4; ++u) {
        float v = csum[u];
        v += __shfl_xor(v, 16); v += __shfl_xor(v, 32);
        if (rq == u) my_cs = v;
        if (is_cross) {
            float w = ccnt[u];
            w += __shfl_xor(w, 16); w += __shfl_xor(w, 32);
            if (rq == u) my_cc = w;
        }
    }
    const int cl_local = wn + rq * 16 + cn;
    redCS[cl_local][wave >> 1] = my_cs;
    redCC[cl_local][wave >> 1] = my_cc;
    __syncthreads();

    if (tid < 128) {
        atomicAdd(&srow[bm + tid], redRS[tid][0] + redRS[tid][1]);
        if (is_cross) atomicAdd(&crow[bm + tid], redRC[tid][0] + redRC[tid][1]);
    } else if (do_cols) {
        const int t2 = tid - 128;
        atomicAdd(&scol[bn + t2], redCS[t2][0] + redCS[t2][1]);
        if (is_cross) atomicAdd(&ccol[bn + t2], redCC[t2][0] + redCC[t2][1]);
    }
}

// Final per-row loss assembly + global sum
__global__ __launch_bounds__(256)
void final_loss(const float* __restrict__ sum_post, const float* __restrict__ cnt_post,
                const float* __restrict__ sum_brand, const float* __restrict__ cnt_brand,
                const float* __restrict__ dvec,
                const float* __restrict__ inv_post, const float* __restrict__ inv_brand,
                float* __restrict__ out) {
    const int i = blockIdx.x * 256 + threadIdx.x;
    float dl = dvec[i] * inv_post[i] * inv_brand[i] * INVT;
    float lp = logf(sum_post[i]);
    float lb = logf(sum_brand[i]);
    float rp = 1.0f / (4096.0f - cnt_post[i]) + 1.0f;
    float rb = 1.0f / (4096.0f - cnt_brand[i]) + 1.0f;
    float loss = 0.5f * (rb * (lb - dl) + rp * (lp - dl));
    #pragma unroll
    for (int off = 32; off > 0; off >>= 1) loss += __shfl_down(loss, off);
    __shared__ float sw[4];
    int wave = threadIdx.x >> 6, lane = threadIdx.x & 63;
    if (lane == 0) sw[wave] = loss;
    __syncthreads();
    if (threadIdx.x == 0) atomicAdd(out, sw[0] + sw[1] + sw[2] + sw[3]);
}

extern "C" void kernel_launch(void* const* d_in, const int* in_sizes, int n_in,
                              void* d_out, int out_size, void* d_ws, size_t ws_size,
                              hipStream_t stream) {
    const float* brand = (const float*)d_in[0];
    const float* post  = (const float*)d_in[1];
    float* out = (float*)d_out;

    char* ws = (char*)d_ws;
    unsigned char* postq  = (unsigned char*)ws;                          // 4 MB
    unsigned char* brandq = postq + (size_t)GN * GK;                     // 4 MB
    float* inv_post  = (float*)(brandq + (size_t)GN * GK);
    float* inv_brand = inv_post + GN;
    float* dvec      = inv_brand + GN;
    float* accs      = dvec + GN;        // [sum_post, sum_brand, cnt_post, cnt_brand]
    float* sum_post  = accs;
    float* sum_brand = accs + GN;
    float* cnt_post  = accs + 2 * GN;
    float* cnt_brand = accs + 3 * GN;

    prep_all<<<GN, 256, 0, stream>>>(brand, post, brandq, postq,
                                     inv_brand, inv_post, dvec, accs, out);
    gemm_all<<<NCROSS + 2 * NTILES, 256, 0, stream>>>(postq, brandq, dvec,
                                                      inv_post, inv_brand,
                                                      sum_post, cnt_post,
                                                      sum_brand, cnt_brand);
    final_loss<<<GN / 256, 256, 0, stream>>>(sum_post, cnt_post, sum_brand, cnt_brand,
                                             dvec, inv_post, inv_brand, out);
}